// Round 1
// baseline (801.595 us; speedup 1.0000x reference)
//
#include <hip/hip_runtime.h>
#include <cstdint>

#define VOCAB  50257
#define BSZ    128
#define KD     8
#define NDRAFT (BSZ * KD)

// ---------------- JAX threefry2x32 (exact) ----------------
__host__ __device__ inline uint32_t rotl32(uint32_t x, int r) {
  return (x << r) | (x >> (32 - r));
}

__host__ __device__ inline void threefry2x32(uint32_t k0, uint32_t k1,
                                             uint32_t x0, uint32_t x1,
                                             uint32_t& o0, uint32_t& o1) {
  uint32_t ks2 = k0 ^ k1 ^ 0x1BD11BDAu;
  x0 += k0; x1 += k1;
  x0 += x1; x1 = rotl32(x1, 13); x1 ^= x0;
  x0 += x1; x1 = rotl32(x1, 15); x1 ^= x0;
  x0 += x1; x1 = rotl32(x1, 26); x1 ^= x0;
  x0 += x1; x1 = rotl32(x1,  6); x1 ^= x0;
  x0 += k1; x1 += ks2 + 1u;
  x0 += x1; x1 = rotl32(x1, 17); x1 ^= x0;
  x0 += x1; x1 = rotl32(x1, 29); x1 ^= x0;
  x0 += x1; x1 = rotl32(x1, 16); x1 ^= x0;
  x0 += x1; x1 = rotl32(x1, 24); x1 ^= x0;
  x0 += ks2; x1 += k0 + 2u;
  x0 += x1; x1 = rotl32(x1, 13); x1 ^= x0;
  x0 += x1; x1 = rotl32(x1, 15); x1 ^= x0;
  x0 += x1; x1 = rotl32(x1, 26); x1 ^= x0;
  x0 += x1; x1 = rotl32(x1,  6); x1 ^= x0;
  x0 += k0; x1 += k1 + 3u;
  x0 += x1; x1 = rotl32(x1, 17); x1 ^= x0;
  x0 += x1; x1 = rotl32(x1, 29); x1 ^= x0;
  x0 += x1; x1 = rotl32(x1, 16); x1 ^= x0;
  x0 += x1; x1 = rotl32(x1, 24); x1 ^= x0;
  x0 += k1; x1 += ks2 + 4u;
  x0 += x1; x1 = rotl32(x1, 13); x1 ^= x0;
  x0 += x1; x1 = rotl32(x1, 15); x1 ^= x0;
  x0 += x1; x1 = rotl32(x1, 26); x1 ^= x0;
  x0 += x1; x1 = rotl32(x1,  6); x1 ^= x0;
  x0 += ks2; x1 += k0 + 5u;
  o0 = x0; o1 = x1;
}

// jax_threefry_partitionable=True (JAX >= 0.5 default):
// 32-bit random bits at flat index i = o0 ^ o1 of threefry(key, hi32(i), lo32(i))
__device__ inline uint32_t tf_bits32(uint32_t k0, uint32_t k1, uint64_t idx) {
  uint32_t o0, o1;
  threefry2x32(k0, k1, (uint32_t)(idx >> 32), (uint32_t)idx, o0, o1);
  return o0 ^ o1;
}

__device__ inline float bits_to_f01(uint32_t bits) {
  // (bits>>9)|0x3f800000 bitcast - 1.0  ->  [0, 1)
  return __uint_as_float((bits >> 9) | 0x3f800000u) - 1.0f;
}

__device__ inline float gumbel_from_bits(uint32_t bits) {
  const float tiny = 1.1754943508222875e-38f;  // finfo(f32).tiny
  float u = fmaxf(tiny, bits_to_f01(bits) + tiny);  // uniform(tiny, 1)
  return -logf(-logf(u));
}

// ---------------- Kernel 1: per-draft-row softmax stats ----------------
__global__ __launch_bounds__(256) void k_stats(const float* __restrict__ logits,
                                               const float* __restrict__ temps,
                                               float* __restrict__ row_max,
                                               float* __restrict__ row_sum) {
  int row = blockIdx.x;          // 0..NDRAFT-1
  int b   = row >> 3;            // row / KD
  float t = temps[b];
  const float* x = logits + (size_t)row * VOCAB;
  __shared__ float sm[256];

  float m = -INFINITY;
  for (int v = threadIdx.x; v < VOCAB; v += 256) m = fmaxf(m, x[v] / t);
  sm[threadIdx.x] = m;
  __syncthreads();
  for (int s = 128; s > 0; s >>= 1) {
    if (threadIdx.x < s) sm[threadIdx.x] = fmaxf(sm[threadIdx.x], sm[threadIdx.x + s]);
    __syncthreads();
  }
  m = sm[0];
  __syncthreads();

  float acc = 0.0f;
  for (int v = threadIdx.x; v < VOCAB; v += 256) acc += expf(x[v] / t - m);
  sm[threadIdx.x] = acc;
  __syncthreads();
  for (int s = 128; s > 0; s >>= 1) {
    if (threadIdx.x < s) sm[threadIdx.x] += sm[threadIdx.x + s];
    __syncthreads();
  }
  if (threadIdx.x == 0) { row_max[row] = m; row_sum[row] = sm[0]; }
}

// ---------------- Kernel 2: accept decisions + n_acc ----------------
__global__ void k_accept(const int* __restrict__ dtok,
                         const float* __restrict__ logits,
                         const float* __restrict__ temps,
                         const float* __restrict__ dprobs,
                         const float* __restrict__ row_max,
                         const float* __restrict__ row_sum,
                         int* __restrict__ n_acc,
                         uint32_t ku0, uint32_t ku1) {
  __shared__ int acc_flags[NDRAFT];
  int i = threadIdx.x;  // 0..NDRAFT-1 (1 block of 1024)
  {
    int b = i >> 3;
    int tok = dtok[i];
    float t  = temps[b];
    float xt = logits[(size_t)i * VOCAB + tok] / t;
    float pt = expf(xt - row_max[i]) / row_sum[i];
    float pd = dprobs[(size_t)i * VOCAB + tok];
    float ap = (pd > 0.0f) ? fminf(1.0f, pt / fmaxf(pd, 1e-30f)) : 0.0f;
    float u  = bits_to_f01(tf_bits32(ku0, ku1, (uint64_t)i));  // uniform(0,1)
    acc_flags[i] = (u <= ap) ? 1 : 0;
  }
  __syncthreads();
  if (i < BSZ) {
    int n = 0;
    for (int j = 0; j < KD; j++) {
      if (acc_flags[i * KD + j]) n++;
      else break;
    }
    n_acc[i] = n;
  }
}

// ---------------- Kernel 3: recovery sampling (only at rejected position) ----
__global__ __launch_bounds__(256) void k_recover(const float* __restrict__ logits,
                                                 const float* __restrict__ temps,
                                                 const float* __restrict__ dprobs,
                                                 const float* __restrict__ row_max,
                                                 const float* __restrict__ row_sum,
                                                 const int* __restrict__ n_acc,
                                                 int* __restrict__ rec_id,
                                                 uint32_t kr0, uint32_t kr1) {
  int b = blockIdx.x;
  int n = n_acc[b];
  if (n >= KD) {                       // all accepted: recovery unused
    if (threadIdx.x == 0) rec_id[b] = 0;
    return;
  }
  int row = b * KD + (n < KD - 1 ? n : KD - 1);
  float t = temps[b];
  const float* x  = logits + (size_t)row * VOCAB;
  const float* pd = dprobs + (size_t)row * VOCAB;
  float m = row_max[row], s = row_sum[row];

  // pass A: does any residual mass exist?  (sum of nonneg f32 > 0 iff any elem > 0)
  __shared__ int anyflag;
  if (threadIdx.x == 0) anyflag = 0;
  __syncthreads();
  int local = 0;
  for (int v = threadIdx.x; v < VOCAB; v += 256) {
    float pt = expf(x[v] / t - m) / s;
    if (pt > pd[v]) { local = 1; break; }
  }
  if (local) atomicOr(&anyflag, 1);
  __syncthreads();
  int usecap = anyflag;

  // pass B: argmax over log(max(rec_dist,1e-30)) + gumbel
  float bestv = -INFINITY; int besti = VOCAB;
  uint64_t base = (uint64_t)row * VOCAB;   // flat idx into (bs,k,vocab)
  for (int v = threadIdx.x; v < VOCAB; v += 256) {
    float pt = expf(x[v] / t - m) / s;
    float rd = usecap ? fmaxf(pt - pd[v], 0.0f) : pt;
    float sc = logf(fmaxf(rd, 1e-30f)) + gumbel_from_bits(tf_bits32(kr0, kr1, base + v));
    if (sc > bestv) { bestv = sc; besti = v; }
  }
  __shared__ float sv[256];
  __shared__ int   si[256];
  sv[threadIdx.x] = bestv; si[threadIdx.x] = besti;
  __syncthreads();
  for (int st = 128; st > 0; st >>= 1) {
    if (threadIdx.x < st) {
      float v2 = sv[threadIdx.x + st]; int i2 = si[threadIdx.x + st];
      if (v2 > sv[threadIdx.x] || (v2 == sv[threadIdx.x] && i2 < si[threadIdx.x])) {
        sv[threadIdx.x] = v2; si[threadIdx.x] = i2;
      }
    }
    __syncthreads();
  }
  if (threadIdx.x == 0) rec_id[b] = si[0];
}

// ---------------- Kernel 4: bonus token (gumbel-max categorical) ----------
__global__ __launch_bounds__(256) void k_bonus(const float* __restrict__ logits,
                                               const float* __restrict__ temps,
                                               int* __restrict__ bon_id,
                                               uint32_t kb0, uint32_t kb1) {
  int b = blockIdx.x;
  float t = temps[b];
  const float* x = logits + (size_t)(NDRAFT + b) * VOCAB;
  uint64_t base = (uint64_t)b * VOCAB;   // flat idx into (bs,vocab)
  float bestv = -INFINITY; int besti = VOCAB;
  for (int v = threadIdx.x; v < VOCAB; v += 256) {
    float sc = x[v] / t + gumbel_from_bits(tf_bits32(kb0, kb1, base + v));
    if (sc > bestv) { bestv = sc; besti = v; }
  }
  __shared__ float sv[256];
  __shared__ int   si[256];
  sv[threadIdx.x] = bestv; si[threadIdx.x] = besti;
  __syncthreads();
  for (int st = 128; st > 0; st >>= 1) {
    if (threadIdx.x < st) {
      float v2 = sv[threadIdx.x + st]; int i2 = si[threadIdx.x + st];
      if (v2 > sv[threadIdx.x] || (v2 == sv[threadIdx.x] && i2 < si[threadIdx.x])) {
        sv[threadIdx.x] = v2; si[threadIdx.x] = i2;
      }
    }
    __syncthreads();
  }
  if (threadIdx.x == 0) bon_id[b] = si[0];
}

// ---------------- Kernel 5: assemble [bs, k+1] output --------------------
__global__ void k_assemble(const int* __restrict__ dtok,
                           const int* __restrict__ n_acc,
                           const int* __restrict__ rec_id,
                           const int* __restrict__ bon_id,
                           int* __restrict__ out) {
  int idx = blockIdx.x * blockDim.x + threadIdx.x;
  if (idx >= BSZ * (KD + 1)) return;
  int b = idx / (KD + 1), p = idx % (KD + 1);
  int n = n_acc[b];
  int val;
  if (p < n)       val = dtok[b * KD + p];
  else if (p == n) val = (n == KD) ? bon_id[b] : rec_id[b];
  else             val = -1;
  out[idx] = val;
}

extern "C" void kernel_launch(void* const* d_in, const int* in_sizes, int n_in,
                              void* d_out, int out_size, void* d_ws, size_t ws_size,
                              hipStream_t stream) {
  const int*   dtok   = (const int*)  d_in[0];
  const float* logits = (const float*)d_in[1];
  const float* temps  = (const float*)d_in[2];
  const float* dprobs = (const float*)d_in[3];
  int* out = (int*)d_out;

  float* row_max = (float*)d_ws;
  float* row_sum = row_max + NDRAFT;
  int*   n_acc   = (int*)(row_sum + NDRAFT);
  int*   rec_id  = n_acc + BSZ;
  int*   bon_id  = rec_id + BSZ;

  // nkey = key(42) -> data (0,42); split(nkey,3) fold-like: subkey_i = threefry(key,(0,i))
  uint32_t ku0, ku1, kr0, kr1, kb0, kb1;
  threefry2x32(0u, 42u, 0u, 0u, ku0, ku1);   // ku       (accept uniforms)
  threefry2x32(0u, 42u, 0u, 1u, kr0, kr1);   // kg_rec   (recovery gumbel)
  threefry2x32(0u, 42u, 0u, 2u, kb0, kb1);   // kg_bonus (bonus gumbel)

  k_stats   <<<NDRAFT, 256, 0, stream>>>(logits, temps, row_max, row_sum);
  k_accept  <<<1, NDRAFT, 0, stream>>>(dtok, logits, temps, dprobs,
                                       row_max, row_sum, n_acc, ku0, ku1);
  k_recover <<<BSZ, 256, 0, stream>>>(logits, temps, dprobs, row_max, row_sum,
                                      n_acc, rec_id, kr0, kr1);
  k_bonus   <<<BSZ, 256, 0, stream>>>(logits, temps, bon_id, kb0, kb1);
  k_assemble<<<(BSZ * (KD + 1) + 255) / 256, 256, 0, stream>>>(dtok, n_acc, rec_id,
                                                               bon_id, out);
}

// Round 2
// 545.867 us; speedup vs baseline: 1.4685x; 1.4685x over previous
//
#include <hip/hip_runtime.h>
#include <cstdint>

#define VOCAB  50257
#define BSZ    128
#define KD     8
#define NDRAFT (BSZ * KD)
#define SEG    16
#define SEGLEN 3142   // ceil(VOCAB/SEG)

// ---------------- JAX threefry2x32 (exact) ----------------
__host__ __device__ inline uint32_t rotl32(uint32_t x, int r) {
  return (x << r) | (x >> (32 - r));
}

__host__ __device__ inline void threefry2x32(uint32_t k0, uint32_t k1,
                                             uint32_t x0, uint32_t x1,
                                             uint32_t& o0, uint32_t& o1) {
  uint32_t ks2 = k0 ^ k1 ^ 0x1BD11BDAu;
  x0 += k0; x1 += k1;
  x0 += x1; x1 = rotl32(x1, 13); x1 ^= x0;
  x0 += x1; x1 = rotl32(x1, 15); x1 ^= x0;
  x0 += x1; x1 = rotl32(x1, 26); x1 ^= x0;
  x0 += x1; x1 = rotl32(x1,  6); x1 ^= x0;
  x0 += k1; x1 += ks2 + 1u;
  x0 += x1; x1 = rotl32(x1, 17); x1 ^= x0;
  x0 += x1; x1 = rotl32(x1, 29); x1 ^= x0;
  x0 += x1; x1 = rotl32(x1, 16); x1 ^= x0;
  x0 += x1; x1 = rotl32(x1, 24); x1 ^= x0;
  x0 += ks2; x1 += k0 + 2u;
  x0 += x1; x1 = rotl32(x1, 13); x1 ^= x0;
  x0 += x1; x1 = rotl32(x1, 15); x1 ^= x0;
  x0 += x1; x1 = rotl32(x1, 26); x1 ^= x0;
  x0 += x1; x1 = rotl32(x1,  6); x1 ^= x0;
  x0 += k0; x1 += k1 + 3u;
  x0 += x1; x1 = rotl32(x1, 17); x1 ^= x0;
  x0 += x1; x1 = rotl32(x1, 29); x1 ^= x0;
  x0 += x1; x1 = rotl32(x1, 16); x1 ^= x0;
  x0 += x1; x1 = rotl32(x1, 24); x1 ^= x0;
  x0 += k1; x1 += ks2 + 4u;
  x0 += x1; x1 = rotl32(x1, 13); x1 ^= x0;
  x0 += x1; x1 = rotl32(x1, 15); x1 ^= x0;
  x0 += x1; x1 = rotl32(x1, 26); x1 ^= x0;
  x0 += x1; x1 = rotl32(x1,  6); x1 ^= x0;
  x0 += ks2; x1 += k0 + 5u;
  o0 = x0; o1 = x1;
}

// jax_threefry_partitionable=True: bits(i) = o0^o1 of threefry(key, hi32(i), lo32(i))
__device__ inline uint32_t tf_bits32(uint32_t k0, uint32_t k1, uint64_t idx) {
  uint32_t o0, o1;
  threefry2x32(k0, k1, (uint32_t)(idx >> 32), (uint32_t)idx, o0, o1);
  return o0 ^ o1;
}

__device__ inline float bits_to_f01(uint32_t bits) {
  return __uint_as_float((bits >> 9) | 0x3f800000u) - 1.0f;
}

__device__ inline float gumbel_from_bits(uint32_t bits) {
  const float tiny = 1.1754943508222875e-38f;
  float u = fmaxf(tiny, bits_to_f01(bits) + tiny);
  return -logf(-logf(u));
}

// ---------------- Kernel 1: per-draft-row softmax stats ----------------
__global__ __launch_bounds__(256) void k_stats(const float* __restrict__ logits,
                                               const float* __restrict__ temps,
                                               float* __restrict__ row_max,
                                               float* __restrict__ row_sum) {
  int row = blockIdx.x;          // 0..NDRAFT-1
  int b   = row >> 3;
  float t = temps[b];
  const float* x = logits + (size_t)row * VOCAB;
  __shared__ float sm[256];

  float m = -INFINITY;
  for (int v = threadIdx.x; v < VOCAB; v += 256) m = fmaxf(m, x[v] / t);
  sm[threadIdx.x] = m;
  __syncthreads();
  for (int s = 128; s > 0; s >>= 1) {
    if (threadIdx.x < s) sm[threadIdx.x] = fmaxf(sm[threadIdx.x], sm[threadIdx.x + s]);
    __syncthreads();
  }
  m = sm[0];
  __syncthreads();

  float acc = 0.0f;
  for (int v = threadIdx.x; v < VOCAB; v += 256) acc += expf(x[v] / t - m);
  sm[threadIdx.x] = acc;
  __syncthreads();
  for (int s = 128; s > 0; s >>= 1) {
    if (threadIdx.x < s) sm[threadIdx.x] += sm[threadIdx.x + s];
    __syncthreads();
  }
  if (threadIdx.x == 0) { row_max[row] = m; row_sum[row] = sm[0]; }
}

// ---------------- Kernel 2: accept decisions + n_acc ----------------
__global__ void k_accept(const int* __restrict__ dtok,
                         const float* __restrict__ logits,
                         const float* __restrict__ temps,
                         const float* __restrict__ dprobs,
                         const float* __restrict__ row_max,
                         const float* __restrict__ row_sum,
                         int* __restrict__ n_acc,
                         uint32_t ku0, uint32_t ku1) {
  __shared__ int acc_flags[NDRAFT];
  int i = threadIdx.x;  // one block of 1024
  {
    int b = i >> 3;
    int tok = dtok[i];
    float t  = temps[b];
    float xt = logits[(size_t)i * VOCAB + tok] / t;
    float pt = expf(xt - row_max[i]) / row_sum[i];
    float pd = dprobs[(size_t)i * VOCAB + tok];
    float ap = (pd > 0.0f) ? fminf(1.0f, pt / fmaxf(pd, 1e-30f)) : 0.0f;
    float u  = bits_to_f01(tf_bits32(ku0, ku1, (uint64_t)i));
    acc_flags[i] = (u <= ap) ? 1 : 0;
  }
  __syncthreads();
  if (i < BSZ) {
    int n = 0;
    for (int j = 0; j < KD; j++) {
      if (acc_flags[i * KD + j]) n++;
      else break;
    }
    n_acc[i] = n;
  }
}

// ---------------- Kernel 3: fused segmented bonus + recovery partials ------
// blocks [0, BSZ*SEG)            : bonus row b = blk/SEG, segment blk%SEG
// blocks [BSZ*SEG, 2*BSZ*SEG)    : recovery for sequence b, segment
__global__ __launch_bounds__(256) void k_partial(const float* __restrict__ logits,
                                                 const float* __restrict__ temps,
                                                 const float* __restrict__ dprobs,
                                                 const float* __restrict__ row_max,
                                                 const float* __restrict__ row_sum,
                                                 const int* __restrict__ n_acc,
                                                 float* __restrict__ bon_v,
                                                 int*   __restrict__ bon_i,
                                                 float* __restrict__ rec_vc,
                                                 int*   __restrict__ rec_ic,
                                                 float* __restrict__ rec_vp,
                                                 int*   __restrict__ rec_ip,
                                                 int*   __restrict__ rec_any,
                                                 uint32_t kb0, uint32_t kb1,
                                                 uint32_t kr0, uint32_t kr1) {
  __shared__ float sv[256];
  __shared__ int   si[256];
  int blk = blockIdx.x;
  int tid = threadIdx.x;

  if (blk < BSZ * SEG) {
    // ---- bonus partial argmax over logits[n_draft+b]/t + gumbel ----
    int b = blk / SEG, seg = blk % SEG;
    int v0 = seg * SEGLEN;
    int v1 = v0 + SEGLEN; if (v1 > VOCAB) v1 = VOCAB;
    float t = temps[b];
    const float* x = logits + (size_t)(NDRAFT + b) * VOCAB;
    uint64_t base = (uint64_t)b * VOCAB;
    float bestv = -INFINITY; int besti = VOCAB;
    for (int v = v0 + tid; v < v1; v += 256) {
      float sc = x[v] / t + gumbel_from_bits(tf_bits32(kb0, kb1, base + v));
      if (sc > bestv) { bestv = sc; besti = v; }
    }
    sv[tid] = bestv; si[tid] = besti;
    __syncthreads();
    for (int st = 128; st > 0; st >>= 1) {
      if (tid < st) {
        float v2 = sv[tid + st]; int i2 = si[tid + st];
        if (v2 > sv[tid] || (v2 == sv[tid] && i2 < si[tid])) { sv[tid] = v2; si[tid] = i2; }
      }
      __syncthreads();
    }
    if (tid == 0) { bon_v[blk] = sv[0]; bon_i[blk] = si[0]; }
  } else {
    // ---- recovery partial: both capped-residual and plain-target argmax ----
    int r = blk - BSZ * SEG;
    int b = r / SEG, seg = r % SEG;
    int n = n_acc[b];
    if (n >= KD) return;                       // all accepted: recovery unused
    int row = b * KD + n;                      // rej_pos = min(n, KD-1) = n here
    int v0 = seg * SEGLEN;
    int v1 = v0 + SEGLEN; if (v1 > VOCAB) v1 = VOCAB;
    float t = temps[b];
    const float* x  = logits + (size_t)row * VOCAB;
    const float* pd = dprobs + (size_t)row * VOCAB;
    float m = row_max[row], s = row_sum[row];
    uint64_t base = (uint64_t)row * VOCAB;

    float bc = -INFINITY; int ic = VOCAB;      // capped residual argmax
    float bp = -INFINITY; int ip = VOCAB;      // plain target argmax
    int any = 0;
    for (int v = v0 + tid; v < v1; v += 256) {
      float pt = expf(x[v] / t - m) / s;
      float diff = pt - pd[v];
      if (diff > 0.0f) any = 1;
      float g  = gumbel_from_bits(tf_bits32(kr0, kr1, base + v));
      float scc = logf(fmaxf(fmaxf(diff, 0.0f), 1e-30f)) + g;
      float scp = logf(fmaxf(pt, 1e-30f)) + g;
      if (scc > bc) { bc = scc; ic = v; }
      if (scp > bp) { bp = scp; ip = v; }
    }
    // reduce capped
    sv[tid] = bc; si[tid] = ic;
    __syncthreads();
    for (int st = 128; st > 0; st >>= 1) {
      if (tid < st) {
        float v2 = sv[tid + st]; int i2 = si[tid + st];
        if (v2 > sv[tid] || (v2 == sv[tid] && i2 < si[tid])) { sv[tid] = v2; si[tid] = i2; }
      }
      __syncthreads();
    }
    if (tid == 0) { rec_vc[r] = sv[0]; rec_ic[r] = si[0]; }
    __syncthreads();
    // reduce plain
    sv[tid] = bp; si[tid] = ip;
    __syncthreads();
    for (int st = 128; st > 0; st >>= 1) {
      if (tid < st) {
        float v2 = sv[tid + st]; int i2 = si[tid + st];
        if (v2 > sv[tid] || (v2 == sv[tid] && i2 < si[tid])) { sv[tid] = v2; si[tid] = i2; }
      }
      __syncthreads();
    }
    if (tid == 0) { rec_vp[r] = sv[0]; rec_ip[r] = si[0]; }
    // reduce any-flag
    si[tid] = any;
    __syncthreads();
    for (int st = 128; st > 0; st >>= 1) {
      if (tid < st) si[tid] |= si[tid + st];
      __syncthreads();
    }
    if (tid == 0) rec_any[r] = si[0];
  }
}

// ---------------- Kernel 4: final reduce + assemble output row --------------
__global__ __launch_bounds__(64) void k_final(const int* __restrict__ dtok,
                                              const int* __restrict__ n_acc,
                                              const float* __restrict__ bon_v,
                                              const int*   __restrict__ bon_i,
                                              const float* __restrict__ rec_vc,
                                              const int*   __restrict__ rec_ic,
                                              const float* __restrict__ rec_vp,
                                              const int*   __restrict__ rec_ip,
                                              const int*   __restrict__ rec_any,
                                              int* __restrict__ out) {
  int b = blockIdx.x;
  int n = n_acc[b];
  __shared__ int s_bon, s_rec;
  if (threadIdx.x == 0) {
    float bv = -INFINITY; int bi = VOCAB;
    for (int s2 = 0; s2 < SEG; s2++) {
      float v = bon_v[b * SEG + s2]; int i = bon_i[b * SEG + s2];
      if (v > bv || (v == bv && i < bi)) { bv = v; bi = i; }
    }
    s_bon = bi;
    s_rec = 0;
    if (n < KD) {
      int any = 0;
      for (int s2 = 0; s2 < SEG; s2++) any |= rec_any[b * SEG + s2];
      const float* rv = any ? rec_vc : rec_vp;
      const int*   ri = any ? rec_ic : rec_ip;
      float cv = -INFINITY; int ci = VOCAB;
      for (int s2 = 0; s2 < SEG; s2++) {
        float v = rv[b * SEG + s2]; int i = ri[b * SEG + s2];
        if (v > cv || (v == cv && i < ci)) { cv = v; ci = i; }
      }
      s_rec = ci;
    }
  }
  __syncthreads();
  if (threadIdx.x <= KD) {
    int p = threadIdx.x;
    int val;
    if (p < n)       val = dtok[b * KD + p];
    else if (p == n) val = (n == KD) ? s_bon : s_rec;
    else             val = -1;
    out[b * (KD + 1) + p] = val;
  }
}

extern "C" void kernel_launch(void* const* d_in, const int* in_sizes, int n_in,
                              void* d_out, int out_size, void* d_ws, size_t ws_size,
                              hipStream_t stream) {
  const int*   dtok   = (const int*)  d_in[0];
  const float* logits = (const float*)d_in[1];
  const float* temps  = (const float*)d_in[2];
  const float* dprobs = (const float*)d_in[3];
  int* out = (int*)d_out;

  float* row_max = (float*)d_ws;                 // [NDRAFT]
  float* row_sum = row_max + NDRAFT;             // [NDRAFT]
  int*   n_acc   = (int*)(row_sum + NDRAFT);     // [BSZ]
  float* bon_v   = (float*)(n_acc + BSZ);        // [BSZ*SEG]
  int*   bon_i   = (int*)(bon_v + BSZ * SEG);    // [BSZ*SEG]
  float* rec_vc  = (float*)(bon_i + BSZ * SEG);  // [BSZ*SEG]
  int*   rec_ic  = (int*)(rec_vc + BSZ * SEG);   // [BSZ*SEG]
  float* rec_vp  = (float*)(rec_ic + BSZ * SEG); // [BSZ*SEG]
  int*   rec_ip  = (int*)(rec_vp + BSZ * SEG);   // [BSZ*SEG]
  int*   rec_any = rec_ip + BSZ * SEG;           // [BSZ*SEG]

  // nkey = key(42); split(nkey,3): subkey_i = threefry(key, (0,i))
  uint32_t ku0, ku1, kr0, kr1, kb0, kb1;
  threefry2x32(0u, 42u, 0u, 0u, ku0, ku1);   // ku       (accept uniforms)
  threefry2x32(0u, 42u, 0u, 1u, kr0, kr1);   // kg_rec   (recovery gumbel)
  threefry2x32(0u, 42u, 0u, 2u, kb0, kb1);   // kg_bonus (bonus gumbel)

  k_stats  <<<NDRAFT, 256, 0, stream>>>(logits, temps, row_max, row_sum);
  k_accept <<<1, NDRAFT, 0, stream>>>(dtok, logits, temps, dprobs,
                                      row_max, row_sum, n_acc, ku0, ku1);
  k_partial<<<2 * BSZ * SEG, 256, 0, stream>>>(logits, temps, dprobs,
                                               row_max, row_sum, n_acc,
                                               bon_v, bon_i, rec_vc, rec_ic,
                                               rec_vp, rec_ip, rec_any,
                                               kb0, kb1, kr0, kr1);
  k_final  <<<BSZ, 64, 0, stream>>>(dtok, n_acc, bon_v, bon_i,
                                    rec_vc, rec_ic, rec_vp, rec_ip, rec_any, out);
}

// Round 3
// 440.124 us; speedup vs baseline: 1.8213x; 1.2403x over previous
//
#include <hip/hip_runtime.h>
#include <cstdint>

#define VOCAB  50257
#define BSZ    128
#define KD     8
#define NDRAFT (BSZ * KD)
#define SEG    16
#define SEGLEN 3142   // ceil(VOCAB/SEG)

// ---------------- JAX threefry2x32 (exact) ----------------
__host__ __device__ inline uint32_t rotl32(uint32_t x, int r) {
  return (x << r) | (x >> (32 - r));
}

__host__ __device__ inline void threefry2x32(uint32_t k0, uint32_t k1,
                                             uint32_t x0, uint32_t x1,
                                             uint32_t& o0, uint32_t& o1) {
  uint32_t ks2 = k0 ^ k1 ^ 0x1BD11BDAu;
  x0 += k0; x1 += k1;
  x0 += x1; x1 = rotl32(x1, 13); x1 ^= x0;
  x0 += x1; x1 = rotl32(x1, 15); x1 ^= x0;
  x0 += x1; x1 = rotl32(x1, 26); x1 ^= x0;
  x0 += x1; x1 = rotl32(x1,  6); x1 ^= x0;
  x0 += k1; x1 += ks2 + 1u;
  x0 += x1; x1 = rotl32(x1, 17); x1 ^= x0;
  x0 += x1; x1 = rotl32(x1, 29); x1 ^= x0;
  x0 += x1; x1 = rotl32(x1, 16); x1 ^= x0;
  x0 += x1; x1 = rotl32(x1, 24); x1 ^= x0;
  x0 += ks2; x1 += k0 + 2u;
  x0 += x1; x1 = rotl32(x1, 13); x1 ^= x0;
  x0 += x1; x1 = rotl32(x1, 15); x1 ^= x0;
  x0 += x1; x1 = rotl32(x1, 26); x1 ^= x0;
  x0 += x1; x1 = rotl32(x1,  6); x1 ^= x0;
  x0 += k0; x1 += k1 + 3u;
  x0 += x1; x1 = rotl32(x1, 17); x1 ^= x0;
  x0 += x1; x1 = rotl32(x1, 29); x1 ^= x0;
  x0 += x1; x1 = rotl32(x1, 16); x1 ^= x0;
  x0 += x1; x1 = rotl32(x1, 24); x1 ^= x0;
  x0 += k1; x1 += ks2 + 4u;
  x0 += x1; x1 = rotl32(x1, 13); x1 ^= x0;
  x0 += x1; x1 = rotl32(x1, 15); x1 ^= x0;
  x0 += x1; x1 = rotl32(x1, 26); x1 ^= x0;
  x0 += x1; x1 = rotl32(x1,  6); x1 ^= x0;
  x0 += ks2; x1 += k0 + 5u;
  o0 = x0; o1 = x1;
}

// jax_threefry_partitionable=True: bits(i) = o0^o1 of threefry(key, hi32(i), lo32(i))
__device__ inline uint32_t tf_bits32(uint32_t k0, uint32_t k1, uint64_t idx) {
  uint32_t o0, o1;
  threefry2x32(k0, k1, (uint32_t)(idx >> 32), (uint32_t)idx, o0, o1);
  return o0 ^ o1;
}

__device__ inline float bits_to_f01(uint32_t bits) {
  return __uint_as_float((bits >> 9) | 0x3f800000u) - 1.0f;
}

// fast-intrinsic gumbel (v_log_f32-based); ~1e-6 abs error vs libm
__device__ inline float gumbel_fast(uint32_t bits) {
  const float tiny = 1.1754943508222875e-38f;
  float u = fmaxf(tiny, bits_to_f01(bits) + tiny);
  return -__logf(-__logf(u));
}

// order-preserving (score, idx) pack; ties -> smallest idx wins under max
__device__ inline unsigned long long pack_si(float s, int idx) {
  uint32_t u = __float_as_uint(s);
  u = (u & 0x80000000u) ? ~u : (u | 0x80000000u);
  return ((unsigned long long)u << 32) | (uint32_t)(VOCAB - idx);
}
__device__ inline int unpack_idx(unsigned long long p) {
  return VOCAB - (int)(p & 0xFFFFFFFFu);
}

// ---- Kernel A: fused one-pass softmax stats (blocks 0..NDRAFT-1) +
//                bonus gumbel-argmax partials (blocks NDRAFT..NDRAFT+BSZ*SEG-1)
__global__ __launch_bounds__(256) void k_stats_bonus(
    const float* __restrict__ logits, const float* __restrict__ temps,
    float* __restrict__ row_max, float* __restrict__ row_sum,
    unsigned long long* __restrict__ bon_pack,
    uint32_t kb0, uint32_t kb1) {
  int tid = threadIdx.x;
  if ((int)blockIdx.x < NDRAFT) {
    // ---------- one-pass online softmax over row ----------
    int row = blockIdx.x;
    float inv_t = 1.0f / temps[row >> 3];
    const float* x = logits + (size_t)row * VOCAB;
    float m_t = -INFINITY, s_t = 0.0f;
    auto upd = [&](float val) {
      float xs = val * inv_t;
      float nm = fmaxf(m_t, xs);
      s_t = s_t * __expf(m_t - nm) + __expf(xs - nm);
      m_t = nm;
    };
    // row base elem offset = row*50257 ≡ row (mod 4) -> alignment prologue
    int pre = (4 - (row & 3)) & 3;
    if (tid < pre) upd(x[tid]);
    int nv = (VOCAB - pre) >> 2;
    const float4* xv = (const float4*)(x + pre);
    for (int i = tid; i < nv; i += 256) {
      float4 q = xv[i];
      upd(q.x); upd(q.y); upd(q.z); upd(q.w);
    }
    for (int v = pre + 4 * nv + tid; v < VOCAB; v += 256) upd(x[v]);

    __shared__ float sm[256], ss[256];
    sm[tid] = m_t; ss[tid] = s_t;
    __syncthreads();
    for (int st = 128; st > 0; st >>= 1) {
      if (tid < st) {
        float m2 = sm[tid + st], s2 = ss[tid + st];
        float M = fmaxf(sm[tid], m2);
        ss[tid] = ss[tid] * __expf(sm[tid] - M) + s2 * __expf(m2 - M);
        sm[tid] = M;
      }
      __syncthreads();
    }
    if (tid == 0) { row_max[row] = sm[0]; row_sum[row] = ss[0]; }
  } else {
    // ---------- bonus segment: argmax(logits/t + gumbel) ----------
    int r = blockIdx.x - NDRAFT;
    int b = r >> 4, seg = r & 15;
    int v0 = seg * SEGLEN;
    int v1 = v0 + SEGLEN; if (v1 > VOCAB) v1 = VOCAB;
    float inv_t = 1.0f / temps[b];
    const float* x = logits + (size_t)(NDRAFT + b) * VOCAB;
    uint64_t base = (uint64_t)b * VOCAB;
    float bv = -INFINITY; int bi = VOCAB;
    for (int v = v0 + tid; v < v1; v += 256) {
      float sc = x[v] * inv_t + gumbel_fast(tf_bits32(kb0, kb1, base + v));
      if (sc > bv) { bv = sc; bi = v; }
    }
    __shared__ unsigned long long sp[256];
    sp[tid] = pack_si(bv, bi);
    __syncthreads();
    for (int st = 128; st > 0; st >>= 1) {
      if (tid < st) { if (sp[tid + st] > sp[tid]) sp[tid] = sp[tid + st]; }
      __syncthreads();
    }
    if (tid == 0) atomicMax(&bon_pack[b], sp[0]);
  }
}

// ---- Kernel B: accept decisions + n_acc (exact libm/div path; 1024 elems)
__global__ void k_accept(const int* __restrict__ dtok,
                         const float* __restrict__ logits,
                         const float* __restrict__ temps,
                         const float* __restrict__ dprobs,
                         const float* __restrict__ row_max,
                         const float* __restrict__ row_sum,
                         int* __restrict__ n_acc,
                         uint32_t ku0, uint32_t ku1) {
  __shared__ int acc_flags[NDRAFT];
  int i = threadIdx.x;  // one block of 1024
  {
    int b = i >> 3;
    int tok = dtok[i];
    float t  = temps[b];
    float xt = logits[(size_t)i * VOCAB + tok] / t;
    float pt = expf(xt - row_max[i]) / row_sum[i];
    float pd = dprobs[(size_t)i * VOCAB + tok];
    float ap = (pd > 0.0f) ? fminf(1.0f, pt / fmaxf(pd, 1e-30f)) : 0.0f;
    float u  = bits_to_f01(tf_bits32(ku0, ku1, (uint64_t)i));
    acc_flags[i] = (u <= ap) ? 1 : 0;
  }
  __syncthreads();
  if (i < BSZ) {
    int n = 0;
    for (int j = 0; j < KD; j++) {
      if (acc_flags[i * KD + j]) n++;
      else break;
    }
    n_acc[i] = n;
  }
}

// ---- Kernel C: recovery segments (capped + plain argmax, any-flag) ----
__global__ __launch_bounds__(256) void k_recover(
    const float* __restrict__ logits, const float* __restrict__ temps,
    const float* __restrict__ dprobs,
    const float* __restrict__ row_max, const float* __restrict__ row_sum,
    const int* __restrict__ n_acc,
    unsigned long long* __restrict__ rec_pc,
    unsigned long long* __restrict__ rec_pp,
    int* __restrict__ rec_any,
    uint32_t kr0, uint32_t kr1) {
  int r = blockIdx.x;
  int b = r >> 4, seg = r & 15;
  int n = n_acc[b];
  if (n >= KD) return;                 // all accepted: recovery unused
  int tid = threadIdx.x;
  int row = b * KD + n;                // rej_pos = min(n, KD-1) = n here
  int v0 = seg * SEGLEN;
  int v1 = v0 + SEGLEN; if (v1 > VOCAB) v1 = VOCAB;
  float inv_t = 1.0f / temps[b];
  float m = row_max[row];
  float inv_s = 1.0f / row_sum[row];
  const float* x  = logits + (size_t)row * VOCAB;
  const float* pd = dprobs + (size_t)row * VOCAB;
  uint64_t base = (uint64_t)row * VOCAB;

  float bc = -INFINITY, bp = -INFINITY;
  int ic = VOCAB, ip = VOCAB, any = 0;
  for (int v = v0 + tid; v < v1; v += 256) {
    float pt = __expf(x[v] * inv_t - m) * inv_s;
    float diff = pt - pd[v];
    if (diff > 0.0f) any = 1;
    float g = gumbel_fast(tf_bits32(kr0, kr1, base + v));
    float scc = __logf(fmaxf(fmaxf(diff, 0.0f), 1e-30f)) + g;
    float scp = __logf(fmaxf(pt, 1e-30f)) + g;
    if (scc > bc) { bc = scc; ic = v; }
    if (scp > bp) { bp = scp; ip = v; }
  }
  __shared__ unsigned long long sp[256];
  __shared__ int sa[256];
  sp[tid] = pack_si(bc, ic); sa[tid] = any;
  __syncthreads();
  for (int st = 128; st > 0; st >>= 1) {
    if (tid < st) {
      if (sp[tid + st] > sp[tid]) sp[tid] = sp[tid + st];
      sa[tid] |= sa[tid + st];
    }
    __syncthreads();
  }
  if (tid == 0) {
    atomicMax(&rec_pc[b], sp[0]);
    if (sa[0]) atomicOr(&rec_any[b], 1);
  }
  __syncthreads();
  sp[tid] = pack_si(bp, ip);
  __syncthreads();
  for (int st = 128; st > 0; st >>= 1) {
    if (tid < st) { if (sp[tid + st] > sp[tid]) sp[tid] = sp[tid + st]; }
    __syncthreads();
  }
  if (tid == 0) atomicMax(&rec_pp[b], sp[0]);
}

// ---- Kernel D: assemble [bs, k+1] output ----
__global__ void k_final(const int* __restrict__ dtok,
                        const int* __restrict__ n_acc,
                        const unsigned long long* __restrict__ bon_pack,
                        const unsigned long long* __restrict__ rec_pc,
                        const unsigned long long* __restrict__ rec_pp,
                        const int* __restrict__ rec_any,
                        int* __restrict__ out) {
  int idx = blockIdx.x * blockDim.x + threadIdx.x;
  if (idx >= BSZ * (KD + 1)) return;
  int b = idx / (KD + 1), p = idx % (KD + 1);
  int n = n_acc[b];
  int val;
  if (p < n)       val = dtok[b * KD + p];
  else if (p == n) {
    if (n == KD) val = unpack_idx(bon_pack[b]);
    else         val = unpack_idx(rec_any[b] ? rec_pc[b] : rec_pp[b]);
  }
  else             val = -1;
  out[idx] = val;
}

extern "C" void kernel_launch(void* const* d_in, const int* in_sizes, int n_in,
                              void* d_out, int out_size, void* d_ws, size_t ws_size,
                              hipStream_t stream) {
  const int*   dtok   = (const int*)  d_in[0];
  const float* logits = (const float*)d_in[1];
  const float* temps  = (const float*)d_in[2];
  const float* dprobs = (const float*)d_in[3];
  int* out = (int*)d_out;

  unsigned long long* bon_pack = (unsigned long long*)d_ws;   // [BSZ]
  unsigned long long* rec_pc   = bon_pack + BSZ;              // [BSZ]
  unsigned long long* rec_pp   = rec_pc + BSZ;                // [BSZ]
  int*   rec_any = (int*)(rec_pp + BSZ);                      // [BSZ]
  float* row_max = (float*)(rec_any + BSZ);                   // [NDRAFT]
  float* row_sum = row_max + NDRAFT;                          // [NDRAFT]
  int*   n_acc   = (int*)(row_sum + NDRAFT);                  // [BSZ]

  // nkey = key(42); split(nkey,3): subkey_i = threefry(key, (0,i))
  uint32_t ku0, ku1, kr0, kr1, kb0, kb1;
  threefry2x32(0u, 42u, 0u, 0u, ku0, ku1);   // ku       (accept uniforms)
  threefry2x32(0u, 42u, 0u, 1u, kr0, kr1);   // kg_rec   (recovery gumbel)
  threefry2x32(0u, 42u, 0u, 2u, kb0, kb1);   // kg_bonus (bonus gumbel)

  // zero the atomic-max destinations (packed -inf < 0 < any real packed score)
  hipMemsetAsync(d_ws, 0, (size_t)(3 * BSZ * 8 + BSZ * 4), stream);

  k_stats_bonus<<<NDRAFT + BSZ * SEG, 256, 0, stream>>>(
      logits, temps, row_max, row_sum, bon_pack, kb0, kb1);
  k_accept<<<1, NDRAFT, 0, stream>>>(dtok, logits, temps, dprobs,
                                     row_max, row_sum, n_acc, ku0, ku1);
  k_recover<<<BSZ * SEG, 256, 0, stream>>>(logits, temps, dprobs,
                                           row_max, row_sum, n_acc,
                                           rec_pc, rec_pp, rec_any, kr0, kr1);
  k_final<<<(BSZ * (KD + 1) + 255) / 256, 256, 0, stream>>>(
      dtok, n_acc, bon_pack, rec_pc, rec_pp, rec_any, out);
}